// Round 14
// baseline (447.974 us; speedup 1.0000x reference)
//
#include <hip/hip_runtime.h>
#include <hip/hip_bf16.h>

typedef unsigned short u16;
typedef unsigned int u32;
typedef __attribute__((ext_vector_type(2))) float f32x2;
typedef __attribute__((ext_vector_type(4))) float f32x4;
typedef __attribute__((ext_vector_type(4))) u16 u16x4;
typedef __attribute__((ext_vector_type(8))) u16 u16x8;
typedef __attribute__((ext_vector_type(8))) __bf16 bf16x8;

#define B_ 32
#define T_ 2048
#define MID_ 1024
#define TOPIC_ 512
#define H_ 256
#define ROWS_ 32
#define NCH_ (T_ / ROWS_)   // 64 chunks per batch
#define CPW_ 8              // chunks per workgroup (grid 256 = 1 WG/CU)

// fp32 -> bf16 RNE
static __device__ __forceinline__ u16 f2bf(float x) {
    u32 u = __float_as_uint(x);
    u = (u + 0x7FFFu + ((u >> 16) & 1u)) >> 16;
    return (u16)u;
}
static __device__ __forceinline__ float bf2f(u32 lo16) {
    return __uint_as_float(lo16 << 16);
}

// ---------------- merged prep ----------------
// blocks 0..255 : Wa row h=blk -> bf16 into layout
//   wa16s[ks:32][tt:16][kgrp:4][rl:16][j:8]  (u16 idx = ks*8192 + tt*512 + kgrp*128 + rl*8 + j)
// blocks 256..287 : enc_out[b][h];  block 288 : vsum.
__global__ __launch_bounds__(256) void k_prep(const float* __restrict__ enc,
                                              const float* __restrict__ Ua_w,
                                              const float* __restrict__ Ua_b,
                                              const float* __restrict__ Wa,
                                              const float* __restrict__ v_w,
                                              float* __restrict__ enc_out,
                                              u16* __restrict__ wa16s,
                                              float* __restrict__ vsum) {
    __shared__ float es[TOPIC_];
    const int blk = blockIdx.x, tid = threadIdx.x;
    if (blk < 256) {
        const int h = blk, k = tid * 4;
        f32x4 w = *(const f32x4*)(Wa + h * MID_ + k);
        u16x4 h4;
        h4[0] = f2bf(w[0]); h4[1] = f2bf(w[1]); h4[2] = f2bf(w[2]); h4[3] = f2bf(w[3]);
        const int tt = h >> 4, rl = h & 15;
        const int ks = k >> 5, kg = (k >> 3) & 3, j = k & 7;
        *(u16x4*)&wa16s[ks * 8192 + tt * 512 + kg * 128 + rl * 8 + j] = h4;
    } else if (blk < 288) {
        const int b = blk - 256;
        es[tid]       = enc[b * TOPIC_ + tid];
        es[tid + 256] = enc[b * TOPIC_ + 256 + tid];
        __syncthreads();
        const float* ua = Ua_w + (size_t)tid * TOPIC_;
        float s = Ua_b[tid];
        #pragma unroll 4
        for (int d = 0; d < TOPIC_; d += 4) {
            f32x4 u = *(const f32x4*)(ua + d);
            s += u[0] * es[d] + u[1] * es[d + 1] + u[2] * es[d + 2] + u[3] * es[d + 3];
        }
        enc_out[b * H_ + tid] = s;
    } else {
        if (tid < 64) {
            const int lane = tid;
            float s = v_w[lane] + v_w[lane + 64] + v_w[lane + 128] + v_w[lane + 192];
            #pragma unroll
            for (int m = 32; m; m >>= 1) s += __shfl_xor(s, m, 64);
            if (lane == 0) *vsum = s;
        }
    }
}

// ---------------- fused: trickle-staged chunk pipeline, 256 threads ----------------
// r9-r13 lesson: 512-thread (8-wave) kernels are HARD-capped at 128 VGPR by hipcc;
// any bulk staging state spills (scratch WRITE 90-160 MB each round). Fix: 256
// threads (4 waves), __launch_bounds__(256,1) -> budget ~512 VGPR, no spill.
// grid 256 (1 WG/CU persistent); each WG: 8 contiguous 32-row chunks of one b.
// Chunk c+1 is staged INSIDE chunk c's barrier-free K-loop, one row per K-step
// (f32x4/thread): step i writes row i-4 (cvt->bf16 -> As[p^1]) and loads row i.
// In-order vmem completion paces the B-ring consumes at HBM rate -> K-loop and
// HBM stream fully overlap. As[p] read / As[p^1] written: disjoint, race-free.
// Wave w owns all 32 rows x cols w*64..+64 (acc[2][4]); B-ring 4 slices deep.
__global__ __launch_bounds__(256, 1) void k_fused(const float* __restrict__ dec,
                                                  const int* __restrict__ masks,
                                                  const float* __restrict__ enc_out,
                                                  const float* __restrict__ v_w,
                                                  const float* __restrict__ vsum_p,
                                                  const u16* __restrict__ wa16s,
                                                  float* __restrict__ po,
                                                  float* __restrict__ pms) {
    __shared__ __attribute__((aligned(16))) u16 As[2][ROWS_ * MID_];  // 128 KB
    __shared__ float partc[4][ROWS_];
    __shared__ float ev[ROWS_];

    const int tid = threadIdx.x;
    const int lane = tid & 63, wave = tid >> 6;        // 4 waves
    const int rl = lane & 15, kgrp = lane >> 4;
    const int wg = blockIdx.x;                 // 0..255
    const int b = wg >> 3;                     // 8 WGs per batch row
    const int cbase = (wg & 7) * CPW_;         // contiguous 8-chunk span
    const int c4 = tid * 4;                    // this thread's 4 staged cols

    // enc/v per-lane registers (this wave's 64 cols = 4 col-tiles)
    float encr[4], vr[4];
    #pragma unroll
    for (int ct = 0; ct < 4; ++ct) {
        const int h = wave * 64 + ct * 16 + rl;
        encr[ct] = enc_out[b * H_ + h];
        vr[ct] = v_w[h];
    }

    // B base: wave's 4 tiles (tt = wave*4 + tc)
    const u16* bb = wa16s + (wave * 4) * 512 + kgrp * 128 + rl * 8;  // +tc*512 +ks*8192
    const int ar0 = rl * MID_,        k0 = rl << 3;
    const int ar1 = (16 + rl) * MID_, k1 = (16 + rl) << 3;
    const int kstart = wave * 8;               // per-wave rotated K order

    // ---- prologue: serial-stage chunk cbase into As[0] ----
    {
        const float* src = dec + (size_t)(b * T_ + cbase * ROWS_) * MID_ + c4;
        #pragma unroll 8
        for (int i = 0; i < 32; ++i) {
            f32x4 v = *(const f32x4*)(src + i * MID_);
            u16x4 h4;
            h4[0] = f2bf(v[0]); h4[1] = f2bf(v[1]); h4[2] = f2bf(v[2]); h4[3] = f2bf(v[3]);
            *(u16x4*)&As[0][i * MID_ + (c4 ^ (i << 3))] = h4;
        }
    }
    __syncthreads();

    #pragma unroll 1
    for (int c = 0; c < CPW_; ++c) {
        const int chunk = cbase + c;
        const int p = c & 1;
        const int grow = b * T_ + chunk * ROWS_;
        const bool stg = (c + 1 < CPW_);
        const float* nsrc = dec + (size_t)(grow + ROWS_) * MID_ + c4;  // next chunk
        u16* dst = &As[p ^ 1][0];

        f32x4 sreg[4];   // trickle ring (static idx after full unroll)

        f32x4 acc[2][4];
        const f32x4 z = {0.f, 0.f, 0.f, 0.f};
        #pragma unroll
        for (int rt = 0; rt < 2; ++rt)
            #pragma unroll
            for (int tc = 0; tc < 4; ++tc) acc[rt][tc] = z;

        // B ring: 4 slices deep x 4 tiles
        bf16x8 br0[4], br1[4], br2[4], br3[4];
        {
            const int s0 = kstart, s1 = (kstart + 1) & 31;
            const int s2 = (kstart + 2) & 31, s3 = (kstart + 3) & 31;
            #pragma unroll
            for (int tc = 0; tc < 4; ++tc) {
                br0[tc] = *(const bf16x8*)(bb + s0 * 8192 + tc * 512);
                br1[tc] = *(const bf16x8*)(bb + s1 * 8192 + tc * 512);
                br2[tc] = *(const bf16x8*)(bb + s2 * 8192 + tc * 512);
                br3[tc] = *(const bf16x8*)(bb + s3 * 8192 + tc * 512);
            }
        }
        bf16x8 afc0 = *(const bf16x8*)&As[p][ar0 + ((kstart * 32 + kgrp * 8) ^ k0)];
        bf16x8 afc1 = *(const bf16x8*)&As[p][ar1 + ((kstart * 32 + kgrp * 8) ^ k1)];

        #pragma unroll
        for (int i = 0; i < 32; ++i) {
            // trickle staging: write row i-4, load row i of next chunk
            if (stg) {
                if (i >= 4) {
                    const int w = i - 4;
                    u16x4 h4;
                    h4[0] = f2bf(sreg[w & 3][0]); h4[1] = f2bf(sreg[w & 3][1]);
                    h4[2] = f2bf(sreg[w & 3][2]); h4[3] = f2bf(sreg[w & 3][3]);
                    *(u16x4*)&dst[w * MID_ + (c4 ^ (w << 3))] = h4;
                }
                sreg[i & 3] = *(const f32x4*)(nsrc + (size_t)i * MID_);
            }
            // next-step A frags
            bf16x8 an0 = afc0, an1 = afc1;
            if (i < 31) {
                const int ksn = (kstart + i + 1) & 31;
                an0 = *(const bf16x8*)&As[p][ar0 + ((ksn * 32 + kgrp * 8) ^ k0)];
                an1 = *(const bf16x8*)&As[p][ar1 + ((ksn * 32 + kgrp * 8) ^ k1)];
            }
            {
                bf16x8* brc = ((i & 3) == 0) ? br0 : ((i & 3) == 1) ? br1
                             : ((i & 3) == 2) ? br2 : br3;
                #pragma unroll
                for (int tc = 0; tc < 4; ++tc) {
                    acc[0][tc] = __builtin_amdgcn_mfma_f32_16x16x32_bf16(afc0, brc[tc], acc[0][tc], 0, 0, 0);
                    acc[1][tc] = __builtin_amdgcn_mfma_f32_16x16x32_bf16(afc1, brc[tc], acc[1][tc], 0, 0, 0);
                }
                if (i < 28) {
                    const int ksp = (kstart + i + 4) & 31;
                    #pragma unroll
                    for (int tc = 0; tc < 4; ++tc)
                        brc[tc] = *(const bf16x8*)(bb + ksp * 8192 + tc * 512);
                }
            }
            afc0 = an0; afc1 = an1;
        }

        // residual staging writes (rows 28..31)
        if (stg) {
            #pragma unroll
            for (int w = 28; w < 32; ++w) {
                u16x4 h4;
                h4[0] = f2bf(sreg[w & 3][0]); h4[1] = f2bf(sreg[w & 3][1]);
                h4[2] = f2bf(sreg[w & 3][2]); h4[3] = f2bf(sreg[w & 3][3]);
                *(u16x4*)&dst[w * MID_ + (c4 ^ (w << 3))] = h4;
            }
        }

        // ---- logits partials ----
        // acc[rt][tc][j] = C[row = rt*16 + kgrp*4 + j][col = wave*64 + tc*16 + rl]
        float part[2][4];
        #pragma unroll
        for (int rt = 0; rt < 2; ++rt)
            #pragma unroll
            for (int j = 0; j < 4; ++j) {
                float pp = 0.f;
                #pragma unroll
                for (int tc = 0; tc < 4; ++tc)
                    pp += vr[tc] * tanhf(encr[tc] + acc[rt][tc][j]);
                part[rt][j] = pp;
            }
        #pragma unroll
        for (int m = 1; m < 16; m <<= 1)
            #pragma unroll
            for (int rt = 0; rt < 2; ++rt)
                #pragma unroll
                for (int j = 0; j < 4; ++j)
                    part[rt][j] += __shfl_xor(part[rt][j], m, 64);
        if (rl == 0) {
            #pragma unroll
            for (int rt = 0; rt < 2; ++rt)
                #pragma unroll
                for (int j = 0; j < 4; ++j)
                    partc[wave][rt * 16 + kgrp * 4 + j] = part[rt][j];
        }
        __syncthreads();   // BAR1 (also publishes As[p^1] staging writes)

        // ---- chunk softmax (32 rows; wave 0) ----
        if (wave == 0) {
            const int r = lane & 31;
            float a = partc[0][r] + partc[1][r] + partc[2][r] + partc[3][r];
            const int mk = masks[grow + r];
            a = mk ? a : -(*vsum_p);          // tanh(-inf) = -1 -> logit = -sum(v)
            float mx = a;
            #pragma unroll
            for (int m = 1; m < 32; m <<= 1) mx = fmaxf(mx, __shfl_xor(mx, m, 64));
            const float e = expf(a - mx);
            float s = e;
            #pragma unroll
            for (int m = 1; m < 32; m <<= 1) s += __shfl_xor(s, m, 64);
            if (lane < 32) ev[r] = e;
            if (lane == 0) {
                pms[(b * NCH_ + chunk) * 2] = mx;
                pms[(b * NCH_ + chunk) * 2 + 1] = s;
            }
        }
        __syncthreads();   // BAR2

        // ---- partial weighted sum from the bf16 As[p] tile (4 cols/thread) ----
        f32x4 o = {0.f, 0.f, 0.f, 0.f};
        #pragma unroll
        for (int t = 0; t < ROWS_; ++t) {
            u16x4 h4 = *(const u16x4*)&As[p][t * MID_ + (c4 ^ (t << 3))];
            const float w = ev[t];
            o[0] += w * bf2f((u32)h4[0]);
            o[1] += w * bf2f((u32)h4[1]);
            o[2] += w * bf2f((u32)h4[2]);
            o[3] += w * bf2f((u32)h4[3]);
        }
        *(f32x4*)&po[(size_t)(b * NCH_ + chunk) * MID_ + c4] = o;

        __syncthreads();   // BARt: wsum(As[p]) done before next iter stages into As[p]
    }
}

// ---------------- combine: out[b][m] = sum_c w_c * o_c[m] ----------------
__global__ __launch_bounds__(256) void k_comb(const float* __restrict__ po,
                                              const float* __restrict__ pms,
                                              float* __restrict__ out) {
    __shared__ float wch[NCH_];
    const int b = blockIdx.x, tid = threadIdx.x;
    if (tid < 64) {
        const float mi = pms[(b * NCH_ + tid) * 2];
        const float si = pms[(b * NCH_ + tid) * 2 + 1];
        float M = mi;
        #pragma unroll
        for (int m = 1; m < 64; m <<= 1) M = fmaxf(M, __shfl_xor(M, m, 64));
        const float w = expf(mi - M);
        float D = si * w;
        #pragma unroll
        for (int m = 1; m < 64; m <<= 1) D += __shfl_xor(D, m, 64);
        wch[tid] = w / D;
    }
    __syncthreads();
    #pragma unroll
    for (int i = 0; i < 4; ++i) {
        const int mcol = i * 256 + tid;
        float s = 0.f;
        for (int c = 0; c < NCH_; ++c)
            s += wch[c] * po[((size_t)b * NCH_ + c) * MID_ + mcol];
        out[b * MID_ + mcol] = s;
    }
}

extern "C" void kernel_launch(void* const* d_in, const int* in_sizes, int n_in,
                              void* d_out, int out_size, void* d_ws, size_t ws_size,
                              hipStream_t stream) {
    const float* enc   = (const float*)d_in[0];
    const float* dec   = (const float*)d_in[1];
    const int*   masks = (const int*)d_in[2];
    const float* Ua_w  = (const float*)d_in[3];
    const float* Ua_b  = (const float*)d_in[4];
    const float* Wa_w  = (const float*)d_in[5];
    const float* v_w   = (const float*)d_in[6];
    float* out = (float*)d_out;

    char* ws = (char*)d_ws;
    float* enc_out = (float*)(ws + 0);        // 32 KB
    float* vsum    = (float*)(ws + 32768);    // 4 B (padded)
    u16*   wa16s   = (u16*)(ws + 65536);      // 512 KB
    float* pms     = (float*)(ws + 589824);   // 16 KB (2048 x {max,sum})
    float* po      = (float*)(ws + 606208);   // 8 MB  (2048 x 1024 partial sums)

    k_prep<<<dim3(289), dim3(256), 0, stream>>>(enc, Ua_w, Ua_b, Wa_w, v_w,
                                                enc_out, wa16s, vsum);
    k_fused<<<dim3(256), dim3(256), 0, stream>>>(dec, masks, enc_out, v_w, vsum,
                                                 wa16s, po, pms);
    k_comb<<<dim3(B_), dim3(256), 0, stream>>>(po, pms, out);
}

// Round 15
// 164.002 us; speedup vs baseline: 2.7315x; 2.7315x over previous
//
#include <hip/hip_runtime.h>
#include <hip/hip_bf16.h>

typedef unsigned short u16;
typedef unsigned int u32;
typedef __attribute__((ext_vector_type(2))) float f32x2;
typedef __attribute__((ext_vector_type(4))) float f32x4;
typedef __attribute__((ext_vector_type(4))) u16 u16x4;
typedef __attribute__((ext_vector_type(8))) u16 u16x8;
typedef __attribute__((ext_vector_type(8))) __bf16 bf16x8;

#define B_ 32
#define T_ 2048
#define MID_ 1024
#define TOPIC_ 512
#define H_ 256
#define ROWS_ 32
#define NCH_ (T_ / ROWS_)   // 64 chunks per batch

// fp32 -> bf16 RNE
static __device__ __forceinline__ u16 f2bf(float x) {
    u32 u = __float_as_uint(x);
    u = (u + 0x7FFFu + ((u >> 16) & 1u)) >> 16;
    return (u16)u;
}
static __device__ __forceinline__ float bf2f(u32 lo16) {
    return __uint_as_float(lo16 << 16);
}

// ---------------- merged prep ----------------
// blocks 0..255 : Wa row h=blk -> bf16 into layout
//   wa16s[ks:32][tt:16][kgrp:4][rl:16][j:8]  (u16 idx = ks*8192 + tt*512 + kgrp*128 + rl*8 + j)
// blocks 256..287 : enc_out[b][h];  block 288 : vsum.
__global__ __launch_bounds__(256) void k_prep(const float* __restrict__ enc,
                                              const float* __restrict__ Ua_w,
                                              const float* __restrict__ Ua_b,
                                              const float* __restrict__ Wa,
                                              const float* __restrict__ v_w,
                                              float* __restrict__ enc_out,
                                              u16* __restrict__ wa16s,
                                              float* __restrict__ vsum) {
    __shared__ float es[TOPIC_];
    const int blk = blockIdx.x, tid = threadIdx.x;
    if (blk < 256) {
        const int h = blk, k = tid * 4;
        f32x4 w = *(const f32x4*)(Wa + h * MID_ + k);
        u16x4 h4;
        h4[0] = f2bf(w[0]); h4[1] = f2bf(w[1]); h4[2] = f2bf(w[2]); h4[3] = f2bf(w[3]);
        const int tt = h >> 4, rl = h & 15;
        const int ks = k >> 5, kg = (k >> 3) & 3, j = k & 7;
        *(u16x4*)&wa16s[ks * 8192 + tt * 512 + kg * 128 + rl * 8 + j] = h4;
    } else if (blk < 288) {
        const int b = blk - 256;
        es[tid]       = enc[b * TOPIC_ + tid];
        es[tid + 256] = enc[b * TOPIC_ + 256 + tid];
        __syncthreads();
        const float* ua = Ua_w + (size_t)tid * TOPIC_;
        float s = Ua_b[tid];
        #pragma unroll 4
        for (int d = 0; d < TOPIC_; d += 4) {
            f32x4 u = *(const f32x4*)(ua + d);
            s += u[0] * es[d] + u[1] * es[d + 1] + u[2] * es[d + 2] + u[3] * es[d + 3];
        }
        enc_out[b * H_ + tid] = s;
    } else {
        if (tid < 64) {
            const int lane = tid;
            float s = v_w[lane] + v_w[lane + 64] + v_w[lane + 128] + v_w[lane + 192];
            #pragma unroll
            for (int m = 32; m; m >>= 1) s += __shfl_xor(s, m, 64);
            if (lane == 0) *vsum = s;
        }
    }
}

// ---------------- fused single-pass kernel (r8 structure @ 256 threads) ----------------
// grid 2048, 256 threads = 4 waves, 2 WGs/CU (LDS ~65 KB).
// r9-r14 lessons: 512-thread WGs are hard-capped at 128 VGPR (r8 ran register-starved);
// 256-thread WGs allocate up to ~256 (r14: VGPR_Count=256). Same r8 phases:
//   [stage dec chunk -> bf16 swizzled LDS, 1 barrier] [barrier-free unrolled K-loop,
//   wave owns 32 rows x 64 cols, B-ring 4-deep, per-wave K rotation] [epilogue].
// + XCD-aware bijective swizzle: each XCD owns 4 whole batch rows (dec L2 locality).
__global__ __launch_bounds__(256) void k_fused(const float* __restrict__ dec,
                                               const int* __restrict__ masks,
                                               const float* __restrict__ enc_out,
                                               const float* __restrict__ v_w,
                                               const float* __restrict__ vsum_p,
                                               const u16* __restrict__ wa16s,
                                               float* __restrict__ po,
                                               float* __restrict__ pms) {
    __shared__ __attribute__((aligned(16))) u16 As[ROWS_ * MID_];   // 64 KB
    __shared__ float partc[4][ROWS_];
    __shared__ float ev[ROWS_];

    const int tid = threadIdx.x;
    const int lane = tid & 63, wave = tid >> 6;        // 4 waves
    const int rl = lane & 15, kgrp = lane >> 4;
    // XCD swizzle: 2048 WGs, 8 XCDs, 256/XCD; XCD x -> data ids [x*256, x*256+256)
    const int wgs = (blockIdx.x & 7) * 256 + (blockIdx.x >> 3);
    const int b = wgs >> 6, chunk = wgs & (NCH_ - 1);
    const int grow = b * T_ + chunk * ROWS_;
    const int c4 = tid * 4;                    // this thread's 4 cols (epilogue)

    // enc/v per-lane registers (this wave's 64 cols = 4 col-tiles)
    float encr[4], vr[4];
    #pragma unroll
    for (int ct = 0; ct < 4; ++ct) {
        const int h = wave * 64 + ct * 16 + rl;
        encr[ct] = enc_out[b * H_ + h];
        vr[ct] = v_w[h];
    }

    // ---- phase 1: stage dec chunk -> bf16 swizzled As (4 batches of 8 f32x4) ----
    {
        const float* src = dec + (size_t)grow * MID_;
        #pragma unroll
        for (int bt = 0; bt < 4; ++bt) {
            f32x4 r[8];
            #pragma unroll
            for (int i = 0; i < 8; ++i) {
                const int ga = tid + (bt * 8 + i) * 256;   // f32x4 granule id, 0..8191
                r[i] = *(const f32x4*)(src + ga * 4);
            }
            #pragma unroll
            for (int i = 0; i < 8; ++i) {
                const int ga = tid + (bt * 8 + i) * 256;
                const int row = ga >> 8, c = (ga & 255) * 4;   // 256 granules/row
                u16x4 h4;
                h4[0] = f2bf(r[i][0]); h4[1] = f2bf(r[i][1]);
                h4[2] = f2bf(r[i][2]); h4[3] = f2bf(r[i][3]);
                *(u16x4*)&As[row * MID_ + (c ^ (row << 3))] = h4;
            }
        }
    }
    __syncthreads();

    // ---- phase 2: barrier-free fully-unrolled K-loop ----
    const u16* bb = wa16s + (wave * 4) * 512 + kgrp * 128 + rl * 8;  // +tc*512 +ks*8192
    const int ar0 = rl * MID_,        k0 = rl << 3;
    const int ar1 = (16 + rl) * MID_, k1 = (16 + rl) << 3;
    const int kstart = wave * 8;               // per-wave rotated K order

    f32x4 acc[2][4];
    const f32x4 z = {0.f, 0.f, 0.f, 0.f};
    #pragma unroll
    for (int rt = 0; rt < 2; ++rt)
        #pragma unroll
        for (int tc = 0; tc < 4; ++tc) acc[rt][tc] = z;

    bf16x8 br0[4], br1[4], br2[4], br3[4];
    {
        const int s0 = kstart, s1 = (kstart + 1) & 31;
        const int s2 = (kstart + 2) & 31, s3 = (kstart + 3) & 31;
        #pragma unroll
        for (int tc = 0; tc < 4; ++tc) {
            br0[tc] = *(const bf16x8*)(bb + s0 * 8192 + tc * 512);
            br1[tc] = *(const bf16x8*)(bb + s1 * 8192 + tc * 512);
            br2[tc] = *(const bf16x8*)(bb + s2 * 8192 + tc * 512);
            br3[tc] = *(const bf16x8*)(bb + s3 * 8192 + tc * 512);
        }
    }
    bf16x8 afc0 = *(const bf16x8*)&As[ar0 + ((kstart * 32 + kgrp * 8) ^ k0)];
    bf16x8 afc1 = *(const bf16x8*)&As[ar1 + ((kstart * 32 + kgrp * 8) ^ k1)];

    #pragma unroll
    for (int i = 0; i < 32; ++i) {
        bf16x8 an0 = afc0, an1 = afc1;
        if (i < 31) {
            const int ksn = (kstart + i + 1) & 31;
            an0 = *(const bf16x8*)&As[ar0 + ((ksn * 32 + kgrp * 8) ^ k0)];
            an1 = *(const bf16x8*)&As[ar1 + ((ksn * 32 + kgrp * 8) ^ k1)];
        }
        {
            bf16x8* brc = ((i & 3) == 0) ? br0 : ((i & 3) == 1) ? br1
                         : ((i & 3) == 2) ? br2 : br3;
            #pragma unroll
            for (int tc = 0; tc < 4; ++tc) {
                acc[0][tc] = __builtin_amdgcn_mfma_f32_16x16x32_bf16(afc0, brc[tc], acc[0][tc], 0, 0, 0);
                acc[1][tc] = __builtin_amdgcn_mfma_f32_16x16x32_bf16(afc1, brc[tc], acc[1][tc], 0, 0, 0);
            }
            if (i < 28) {
                const int ksp = (kstart + i + 4) & 31;
                #pragma unroll
                for (int tc = 0; tc < 4; ++tc)
                    brc[tc] = *(const bf16x8*)(bb + ksp * 8192 + tc * 512);
            }
        }
        afc0 = an0; afc1 = an1;
    }

    // ---- phase 3a: logits partials ----
    // acc[rt][tc][j] = C[row = rt*16 + kgrp*4 + j][col = wave*64 + tc*16 + rl]
    float part[2][4];
    #pragma unroll
    for (int rt = 0; rt < 2; ++rt)
        #pragma unroll
        for (int j = 0; j < 4; ++j) {
            float pp = 0.f;
            #pragma unroll
            for (int tc = 0; tc < 4; ++tc)
                pp += vr[tc] * tanhf(encr[tc] + acc[rt][tc][j]);
            part[rt][j] = pp;
        }
    #pragma unroll
    for (int m = 1; m < 16; m <<= 1)
        #pragma unroll
        for (int rt = 0; rt < 2; ++rt)
            #pragma unroll
            for (int j = 0; j < 4; ++j)
                part[rt][j] += __shfl_xor(part[rt][j], m, 64);
    if (rl == 0) {
        #pragma unroll
        for (int rt = 0; rt < 2; ++rt)
            #pragma unroll
            for (int j = 0; j < 4; ++j)
                partc[wave][rt * 16 + kgrp * 4 + j] = part[rt][j];
    }
    __syncthreads();

    // ---- phase 3b: chunk softmax (32 rows; wave 0, lanes duplicate 2x) ----
    if (wave == 0) {
        const int r = lane & 31;
        float a = partc[0][r] + partc[1][r] + partc[2][r] + partc[3][r];
        const int mk = masks[grow + r];
        a = mk ? a : -(*vsum_p);          // tanh(-inf) = -1 -> logit = -sum(v)
        float mx = a;
        #pragma unroll
        for (int m = 1; m < 32; m <<= 1) mx = fmaxf(mx, __shfl_xor(mx, m, 64));
        const float e = expf(a - mx);
        float s = e;
        #pragma unroll
        for (int m = 1; m < 32; m <<= 1) s += __shfl_xor(s, m, 64);
        if (lane < 32) ev[r] = e;
        if (lane == 0) {
            pms[(b * NCH_ + chunk) * 2] = mx;
            pms[(b * NCH_ + chunk) * 2 + 1] = s;
        }
    }
    __syncthreads();

    // ---- phase 3c: partial weighted sum from the bf16 As tile (4 cols/thread) ----
    f32x4 o = {0.f, 0.f, 0.f, 0.f};
    #pragma unroll
    for (int t = 0; t < ROWS_; ++t) {
        u16x4 h4 = *(const u16x4*)&As[t * MID_ + (c4 ^ (t << 3))];
        const float w = ev[t];
        o[0] += w * bf2f((u32)h4[0]);
        o[1] += w * bf2f((u32)h4[1]);
        o[2] += w * bf2f((u32)h4[2]);
        o[3] += w * bf2f((u32)h4[3]);
    }
    *(f32x4*)&po[(size_t)(b * NCH_ + chunk) * MID_ + c4] = o;
}

// ---------------- combine: out[b][m] = sum_c w_c * o_c[m] ----------------
__global__ __launch_bounds__(256) void k_comb(const float* __restrict__ po,
                                              const float* __restrict__ pms,
                                              float* __restrict__ out) {
    __shared__ float wch[NCH_];
    const int b = blockIdx.x, tid = threadIdx.x;
    if (tid < 64) {
        const float mi = pms[(b * NCH_ + tid) * 2];
        const float si = pms[(b * NCH_ + tid) * 2 + 1];
        float M = mi;
        #pragma unroll
        for (int m = 1; m < 64; m <<= 1) M = fmaxf(M, __shfl_xor(M, m, 64));
        const float w = expf(mi - M);
        float D = si * w;
        #pragma unroll
        for (int m = 1; m < 64; m <<= 1) D += __shfl_xor(D, m, 64);
        wch[tid] = w / D;
    }
    __syncthreads();
    #pragma unroll
    for (int i = 0; i < 4; ++i) {
        const int mcol = i * 256 + tid;
        float s = 0.f;
        for (int c = 0; c < NCH_; ++c)
            s += wch[c] * po[((size_t)b * NCH_ + c) * MID_ + mcol];
        out[b * MID_ + mcol] = s;
    }
}

extern "C" void kernel_launch(void* const* d_in, const int* in_sizes, int n_in,
                              void* d_out, int out_size, void* d_ws, size_t ws_size,
                              hipStream_t stream) {
    const float* enc   = (const float*)d_in[0];
    const float* dec   = (const float*)d_in[1];
    const int*   masks = (const int*)d_in[2];
    const float* Ua_w  = (const float*)d_in[3];
    const float* Ua_b  = (const float*)d_in[4];
    const float* Wa_w  = (const float*)d_in[5];
    const float* v_w   = (const float*)d_in[6];
    float* out = (float*)d_out;

    char* ws = (char*)d_ws;
    float* enc_out = (float*)(ws + 0);        // 32 KB
    float* vsum    = (float*)(ws + 32768);    // 4 B (padded)
    u16*   wa16s   = (u16*)(ws + 65536);      // 512 KB
    float* pms     = (float*)(ws + 589824);   // 16 KB (2048 x {max,sum})
    float* po      = (float*)(ws + 606208);   // 8 MB  (2048 x 1024 partial sums)

    k_prep<<<dim3(289), dim3(256), 0, stream>>>(enc, Ua_w, Ua_b, Wa_w, v_w,
                                                enc_out, wa16s, vsum);
    k_fused<<<dim3(B_ * NCH_), dim3(256), 0, stream>>>(dec, masks, enc_out, v_w, vsum,
                                                       wa16s, po, pms);
    k_comb<<<dim3(B_), dim3(256), 0, stream>>>(po, pms, out);
}

// Round 16
// 153.877 us; speedup vs baseline: 2.9113x; 1.0658x over previous
//
#include <hip/hip_runtime.h>
#include <hip/hip_bf16.h>

typedef unsigned short u16;
typedef unsigned int u32;
typedef __attribute__((ext_vector_type(4))) float f32x4;
typedef __attribute__((ext_vector_type(4))) u16 u16x4;
typedef __attribute__((ext_vector_type(8))) u16 u16x8;
typedef __attribute__((ext_vector_type(8))) __bf16 bf16x8;

#define B_ 32
#define T_ 2048
#define MID_ 1024
#define TOPIC_ 512
#define H_ 256

// fp32 -> bf16 RNE
static __device__ __forceinline__ u16 f2bf(float x) {
    u32 u = __float_as_uint(x);
    u = (u + 0x7FFFu + ((u >> 16) & 1u)) >> 16;
    return (u16)u;
}

static __device__ __forceinline__ void gl_lds16(const u16* g, u16* l) {
    __builtin_amdgcn_global_load_lds((const __attribute__((address_space(1))) void*)(const void*)g,
                                     (__attribute__((address_space(3))) void*)(void*)l,
                                     16, 0, 0);
}

// ---------------- merged prep ----------------
// blocks 0..255 : Wa row h=blk -> bf16 into layout
//   wa16s[ks:32][tt:16][kgrp:4][rl:16][j:8]  (u16 idx = ks*8192 + tt*512 + kgrp*128 + rl*8 + j)
// blocks 256..287 : enc_out[b][h];  block 288 : vsum.
__global__ __launch_bounds__(256) void k_prep(const float* __restrict__ enc,
                                              const float* __restrict__ Ua_w,
                                              const float* __restrict__ Ua_b,
                                              const float* __restrict__ Wa,
                                              const float* __restrict__ v_w,
                                              float* __restrict__ enc_out,
                                              u16* __restrict__ wa16s,
                                              float* __restrict__ vsum) {
    __shared__ float es[TOPIC_];
    const int blk = blockIdx.x, tid = threadIdx.x;
    if (blk < 256) {
        const int h = blk, k = tid * 4;
        f32x4 w = *(const f32x4*)(Wa + h * MID_ + k);
        u16x4 h4;
        h4[0] = f2bf(w[0]); h4[1] = f2bf(w[1]); h4[2] = f2bf(w[2]); h4[3] = f2bf(w[3]);
        const int tt = h >> 4, rl = h & 15;
        const int ks = k >> 5, kg = (k >> 3) & 3, j = k & 7;
        *(u16x4*)&wa16s[ks * 8192 + tt * 512 + kg * 128 + rl * 8 + j] = h4;
    } else if (blk < 288) {
        const int b = blk - 256;
        es[tid]       = enc[b * TOPIC_ + tid];
        es[tid + 256] = enc[b * TOPIC_ + 256 + tid];
        __syncthreads();
        const float* ua = Ua_w + (size_t)tid * TOPIC_;
        float s = Ua_b[tid];
        #pragma unroll 4
        for (int d = 0; d < TOPIC_; d += 4) {
            f32x4 u = *(const f32x4*)(ua + d);
            s += u[0] * es[d] + u[1] * es[d + 1] + u[2] * es[d + 2] + u[3] * es[d + 3];
        }
        enc_out[b * H_ + tid] = s;
    } else {
        if (tid < 64) {
            const int lane = tid;
            float s = v_w[lane] + v_w[lane + 64] + v_w[lane + 128] + v_w[lane + 192];
            #pragma unroll
            for (int m = 32; m; m >>= 1) s += __shfl_xor(s, m, 64);
            if (lane == 0) *vsum = s;
        }
    }
}

// ---------------- pass 1: logits GEMM, occupancy-first ----------------
// grid 1024 (M=64/WG), 256 threads = 4 waves; wave owns 16 rows x ALL 256 cols
// (acc[16] f32x4, 16 MFMA/step) -> v-tanh reduce is wave-local (no cross-wave LDS).
// A: direct global->reg (frag = 2 f32x4 from row-major dec; zero redundancy).
// B: Bb[2][8192] db (32 KB) via global_load_lds; ONE barrier/step.
// enc/v in LDS. __launch_bounds__(256,4) pins VGPR<=128 -> 4 WGs/CU, 16 waves/CU:
// four independently-phased WGs cover each other's barrier vmcnt drains.
__global__ __launch_bounds__(256, 4) void k_logits3(const float* __restrict__ dec,
                                                    const int* __restrict__ masks,
                                                    const float* __restrict__ enc_out,
                                                    const float* __restrict__ v_w,
                                                    const float* __restrict__ vsum_p,
                                                    const u16* __restrict__ wa16s,
                                                    float* __restrict__ a_out) {
    __shared__ __attribute__((aligned(16))) u16 Bb[2][8192];   // 32 KB
    __shared__ float encs[H_];
    __shared__ float vs[H_];

    const int tid = threadIdx.x;
    const int lane = tid & 63, wave = tid >> 6;
    const int rl = lane & 15, kgrp = lane >> 4;
    const int wg = blockIdx.x;                 // 0..1023
    const int b = wg >> 5;                     // 32 WGs per batch row
    const int grow = b * T_ + (wg & 31) * 64;  // first of this WG's 64 rows

    encs[tid] = enc_out[b * H_ + tid];
    vs[tid] = v_w[tid];

    // A: this lane's fragment source = dec[grow + wave*16 + rl][ks*32 + kgrp*8 ..+8)
    const float* arow = dec + (size_t)(grow + wave * 16 + rl) * MID_ + kgrp * 8;

    // B staging: per-wave quarter of each 16KB slice (4 gl_lds calls/wave/slice)
    const u16* bsrc = wa16s + wave * 2048 + lane * 8;   // + i*512 + ks*8192

    f32x4 acc[16];
    const f32x4 z = {0.f, 0.f, 0.f, 0.f};
    #pragma unroll
    for (int i = 0; i < 16; ++i) acc[i] = z;

    // ---- prologue: B(0) -> Bb[0]; A(0) -> regs ----
    #pragma unroll
    for (int i = 0; i < 4; ++i)
        gl_lds16(bsrc + i * 512, &Bb[0][wave * 2048 + i * 512]);
    f32x4 a0 = *(const f32x4*)(arow);
    f32x4 a1 = *(const f32x4*)(arow + 4);
    __syncthreads();

    #pragma unroll 1
    for (int ks = 0; ks < 32; ++ks) {
        const int p = ks & 1;
        // stage B(ks+1) into the other buffer (in flight until next barrier)
        if (ks < 31) {
            const u16* s = bsrc + (ks + 1) * 8192;
            u16* d = &Bb[p ^ 1][wave * 2048];
            #pragma unroll
            for (int i = 0; i < 4; ++i) gl_lds16(s + i * 512, d + i * 512);
        }
        // A-frag for this step; then issue next A loads
        u16x8 au;
        #pragma unroll
        for (int i = 0; i < 4; ++i) { au[i] = f2bf(a0[i]); au[4 + i] = f2bf(a1[i]); }
        const bf16x8 af = __builtin_bit_cast(bf16x8, au);
        if (ks < 31) {
            a0 = *(const f32x4*)(arow + (ks + 1) * 32);
            a1 = *(const f32x4*)(arow + (ks + 1) * 32 + 4);
        }
        // 16 MFMAs against the resident B slice
        #pragma unroll
        for (int tc = 0; tc < 16; ++tc) {
            bf16x8 bf = *(const bf16x8*)&Bb[p][tc * 512 + kgrp * 128 + rl * 8];
            acc[tc] = __builtin_amdgcn_mfma_f32_16x16x32_bf16(af, bf, acc[tc], 0, 0, 0);
        }
        __syncthreads();
    }

    // ---- epilogue: logit[row] = sum_h v[h]*tanh(enc[h]+S[row][h]) ----
    // acc[tc][j] = C[row = wave*16 + kgrp*4 + j][col = tc*16 + rl]
    float part[4];
    #pragma unroll
    for (int j = 0; j < 4; ++j) {
        float p = 0.f;
        #pragma unroll
        for (int tc = 0; tc < 16; ++tc) {
            const int col = tc * 16 + rl;
            p += vs[col] * tanhf(encs[col] + acc[tc][j]);
        }
        part[j] = p;
    }
    #pragma unroll
    for (int m = 1; m < 16; m <<= 1)
        #pragma unroll
        for (int j = 0; j < 4; ++j)
            part[j] += __shfl_xor(part[j], m, 64);
    if (rl == 0) {
        const float nvs = -(*vsum_p);   // tanh(-inf) = -1 -> masked logit = -sum(v)
        #pragma unroll
        for (int j = 0; j < 4; ++j) {
            const int row = wave * 16 + kgrp * 4 + j;
            const int t = (grow + row) & (T_ - 1);
            a_out[grow + row] = masks[b * T_ + t] ? part[j] : nvs;
        }
    }
}

// ---------------- softmax over T per b ----------------
__global__ __launch_bounds__(256) void k_softmax(const float* __restrict__ a_buf,
                                                 float* __restrict__ r_buf) {
    const int b = blockIdx.x, tid = threadIdx.x;
    const int wave = tid >> 6, lane = tid & 63;
    __shared__ float wred[4];
    float l[8];
    float m = -1e30f;
    #pragma unroll
    for (int i = 0; i < 8; ++i) {
        l[i] = a_buf[b * T_ + tid + 256 * i];
        m = fmaxf(m, l[i]);
    }
    #pragma unroll
    for (int msk = 32; msk; msk >>= 1) m = fmaxf(m, __shfl_xor(m, msk, 64));
    if (lane == 0) wred[wave] = m;
    __syncthreads();
    m = fmaxf(fmaxf(wred[0], wred[1]), fmaxf(wred[2], wred[3]));
    __syncthreads();
    float e[8];
    float s = 0.f;
    #pragma unroll
    for (int i = 0; i < 8; ++i) { e[i] = expf(l[i] - m); s += e[i]; }
    #pragma unroll
    for (int msk = 32; msk; msk >>= 1) s += __shfl_xor(s, msk, 64);
    if (lane == 0) wred[wave] = s;
    __syncthreads();
    s = wred[0] + wred[1] + wred[2] + wred[3];
    const float inv = 1.0f / s;
    #pragma unroll
    for (int i = 0; i < 8; ++i) r_buf[b * T_ + tid + 256 * i] = e[i] * inv;
}

// ---------------- weighted sum over 128-row chunks (87% HBM proven) ----------------
__global__ __launch_bounds__(256) void k_wsum(const float* __restrict__ dec,
                                              const float* __restrict__ r_buf,
                                              float* __restrict__ partials) {
    const int tc = blockIdx.x, b = blockIdx.y, tid = threadIdx.x;
    const float* base = dec + ((size_t)b * T_ + tc * 128) * MID_ + tid * 4;
    const float* rp = r_buf + b * T_ + tc * 128;
    f32x4 acc = {0.f, 0.f, 0.f, 0.f};
    #pragma unroll 4
    for (int i = 0; i < 128; ++i) {
        const float w = rp[i];
        f32x4 d4 = *(const f32x4*)(base + (size_t)i * MID_);
        acc += d4 * w;
    }
    *(f32x4*)(partials + ((b * 16 + tc) * MID_) + tid * 4) = acc;
}

// out[b][m] = sum_tc partials[b][tc][m]
__global__ __launch_bounds__(256) void k_final(const float* __restrict__ partials,
                                               float* __restrict__ out) {
    const int idx = blockIdx.x * 256 + threadIdx.x;  // 0..32767
    const int b = idx >> 10, mcol = idx & 1023;
    float s = 0.f;
    #pragma unroll
    for (int tc = 0; tc < 16; ++tc) s += partials[(b * 16 + tc) * MID_ + mcol];
    out[idx] = s;
}

extern "C" void kernel_launch(void* const* d_in, const int* in_sizes, int n_in,
                              void* d_out, int out_size, void* d_ws, size_t ws_size,
                              hipStream_t stream) {
    const float* enc   = (const float*)d_in[0];
    const float* dec   = (const float*)d_in[1];
    const int*   masks = (const int*)d_in[2];
    const float* Ua_w  = (const float*)d_in[3];
    const float* Ua_b  = (const float*)d_in[4];
    const float* Wa_w  = (const float*)d_in[5];
    const float* v_w   = (const float*)d_in[6];
    float* out = (float*)d_out;

    char* ws = (char*)d_ws;
    float* enc_out  = (float*)(ws + 0);        // 32 KB
    float* vsum     = (float*)(ws + 32768);    // 4 B (padded)
    u16*   wa16s    = (u16*)(ws + 65536);      // 512 KB
    float* a_buf    = (float*)(ws + 589824);   // 256 KB
    float* r_buf    = (float*)(ws + 851968);   // 256 KB
    float* partials = (float*)(ws + 1114112);  // 2 MB

    k_prep<<<dim3(289), dim3(256), 0, stream>>>(enc, Ua_w, Ua_b, Wa_w, v_w,
                                                enc_out, wa16s, vsum);
    k_logits3<<<dim3(1024), dim3(256), 0, stream>>>(dec, masks, enc_out, v_w, vsum,
                                                    wa16s, a_buf);
    k_softmax<<<dim3(B_), dim3(256), 0, stream>>>(a_buf, r_buf);
    k_wsum<<<dim3(16, B_), dim3(256), 0, stream>>>(dec, r_buf, partials);
    k_final<<<dim3(128), dim3(256), 0, stream>>>(partials, out);
}